// Round 9
// baseline (83.558 us; speedup 1.0000x reference)
//
#include <hip/hip_runtime.h>
#include <hip/hip_bf16.h>
#include <stdint.h>

typedef __bf16 bf16_t;
typedef __bf16 bf16x8 __attribute__((ext_vector_type(8)));
typedef float f32x16 __attribute__((ext_vector_type(16)));

#define NKT 16  // K-tiles: 1024 / 64

// ---- global -> LDS direct load, 16 B per lane (dest = wave-uniform base + lane*16) ----
__device__ __forceinline__ void gload_lds16(const void* g, void* l) {
  using gptr_t = const __attribute__((address_space(1))) void*;
  using lptr_t = __attribute__((address_space(3))) void*;
  gptr_t gp = (gptr_t)(uintptr_t)g;
  lptr_t lp = (lptr_t)(uint32_t)(uintptr_t)l;
  __builtin_amdgcn_global_load_lds(gp, lp, 16, 0, 0);
}

__device__ __forceinline__ bf16x8 cvt8v(const float* __restrict__ src, int i8) {
  const float4* s = reinterpret_cast<const float4*>(src) + (size_t)i8 * 2;
  float4 a = s[0], b = s[1];
  bf16x8 o;
  o[0] = (bf16_t)a.x; o[1] = (bf16_t)a.y; o[2] = (bf16_t)a.z; o[3] = (bf16_t)a.w;
  o[4] = (bf16_t)b.x; o[5] = (bf16_t)b.y; o[6] = (bf16_t)b.z; o[7] = (bf16_t)b.w;
  return o;
}

// converts q->qb, Wk/Wv -> interleaved Wkv (row 2j = Wk_j, 2j+1 = Wv_j), Wq->Wqb, bk/bv->bkv
__global__ __launch_bounds__(256) void cvt_all(const float* __restrict__ q,
                                               const float* __restrict__ Wk,
                                               const float* __restrict__ Wv,
                                               const float* __restrict__ Wq,
                                               const float* __restrict__ bk,
                                               const float* __restrict__ bv,
                                               bf16_t* __restrict__ qb,
                                               bf16_t* __restrict__ Wkv,
                                               bf16_t* __restrict__ Wqb,
                                               float* __restrict__ bkv) {
  const int b = blockIdx.x;
  const int t = threadIdx.x;
  if (b < 4096) {
    int i = b * 256 + t;
    *reinterpret_cast<bf16x8*>(qb + (size_t)i * 8) = cvt8v(q, i);
  } else if (b < 4608) {
    int i = (b - 4096) * 256 + t;
    int j = i >> 7, c8 = i & 127;
    *reinterpret_cast<bf16x8*>(Wkv + (size_t)j * 2048 + c8 * 8) = cvt8v(Wk, i);
  } else if (b < 5120) {
    int i = (b - 4608) * 256 + t;
    int j = i >> 7, c8 = i & 127;
    *reinterpret_cast<bf16x8*>(Wkv + (size_t)j * 2048 + 1024 + c8 * 8) = cvt8v(Wv, i);
  } else if (b < 5632) {
    int i = (b - 5120) * 256 + t;
    *reinterpret_cast<bf16x8*>(Wqb + (size_t)i * 8) = cvt8v(Wq, i);
  } else {
#pragma unroll
    for (int u = 0; u < 4; ++u) {
      int j = t * 4 + u;
      bkv[2 * j] = bk[j];
      bkv[2 * j + 1] = bv[j];
    }
  }
}

// ======================= fused KV GEMM (8-wave, 32x32x16 MFMA) =======================
// A: qb [8192][1024], Bkv: interleaved [2048][1024]. BM=256, BN=256, BK=64.
// grid 256 (32 m x 8 n), 512 threads = 8 waves (2M x 4N); wave tile 128x64 = 4x2 frags.
// 2 phases/K-tile (ks 0-1, ks 2-3), 16 MFMA each; 3 barriers/tile.
// Epilogue: column-pair exp-reduction -> pden/pnum[32][1024].
__global__ __launch_bounds__(512, 1) void gemm_kv32(const bf16_t* __restrict__ A,
                                                    const bf16_t* __restrict__ Bkv,
                                                    const float* __restrict__ bkv,
                                                    float* __restrict__ pden,
                                                    float* __restrict__ pnum) {
  __shared__ bf16_t lA[2 * 256 * 64];
  __shared__ bf16_t lB[2 * 256 * 64];
  __shared__ float sD[2][128];
  __shared__ float sN[2][128];

  const int tid = threadIdx.x;
  const int w = tid >> 6, l = tid & 63;
  const int kwr = w >> 2, kwc = w & 3;         // 2M x 4N waves
  const int swz = (blockIdx.x & 7) * 32 + (blockIdx.x >> 3);  // XCD chunking (256%8==0)
  const int bx = swz & 7, by = swz >> 3;
  const int m0 = by * 256, n0 = bx * 256;

  const int rl3 = l >> 3;
  const int scol = ((l & 7) ^ rl3) * 8;        // pre-swizzled global source chunk
  const int l31 = l & 31, lhi = l >> 5, sw = l & 7;

  const bf16_t* Ab = A + (size_t)(m0 + w * 8 + rl3) * 1024 + scol;
  const bf16_t* Bb = Bkv + (size_t)(n0 + w * 8 + rl3) * 1024 + scol;

  f32x16 acc[4][2];
#pragma unroll
  for (int m = 0; m < 4; ++m)
#pragma unroll
    for (int n = 0; n < 2; ++n) acc[m][n] = (f32x16){0.f};

#define STAGE_A(kt, h, r, slot)                                              \
  gload_lds16(Ab + (size_t)((h) * 128 + (r) * 64) * 1024 + (kt) * 64,        \
              &lA[(slot) * 16384 + ((h) * 128 + (r) * 64 + w * 8) * 64])
#define STAGE_B(kt, h, r, slot)                                              \
  gload_lds16(Bb + (size_t)((h) * 128 + (r) * 64) * 1024 + (kt) * 64,        \
              &lB[(slot) * 16384 + ((h) * 128 + (r) * 64 + w * 8) * 64])
// 32x32 fragment reads: row = base + mt*32 + (l&31), k-chunk = ks*2 + (l>>5), XOR l&7
#define RD_A(mt, ks) \
  (*reinterpret_cast<const bf16x8*>(&lA[slot * 16384 + (kwr * 128 + (mt) * 32 + l31) * 64 + ((((ks) * 2) + lhi) ^ sw) * 8]))
#define RD_B(nt, ks) \
  (*reinterpret_cast<const bf16x8*>(&lB[slot * 16384 + (kwc * 64 + (nt) * 32 + l31) * 64 + ((((ks) * 2) + lhi) ^ sw) * 8]))

  STAGE_A(0, 0, 0, 0); STAGE_A(0, 0, 1, 0); STAGE_A(0, 1, 0, 0); STAGE_A(0, 1, 1, 0);
  STAGE_B(0, 0, 0, 0); STAGE_B(0, 0, 1, 0); STAGE_B(0, 1, 0, 0); STAGE_B(0, 1, 1, 0);

#pragma unroll 1
  for (int T = 0; T < NKT; ++T) {
    const int slot = T & 1, ns = slot ^ 1;
    const bool pf = (T + 1) < NKT;
    if (pf) { STAGE_A(T + 1, 0, 0, ns); STAGE_A(T + 1, 0, 1, ns); }
    if (pf) asm volatile("s_waitcnt vmcnt(2)" ::: "memory");
    else    asm volatile("s_waitcnt vmcnt(0)" ::: "memory");
    __builtin_amdgcn_s_barrier();
    __builtin_amdgcn_sched_barrier(0);

    bf16x8 af[4], ag[4], b0[2], b1[2];
    // ---- phase 1: ks 0,1 ----
#pragma unroll
    for (int nt = 0; nt < 2; ++nt) { b0[nt] = RD_B(nt, 0); b1[nt] = RD_B(nt, 1); }
#pragma unroll
    for (int mt = 0; mt < 4; ++mt) { af[mt] = RD_A(mt, 0); ag[mt] = RD_A(mt, 1); }
    if (pf) { STAGE_A(T + 1, 1, 0, ns); STAGE_A(T + 1, 1, 1, ns);
              STAGE_B(T + 1, 0, 0, ns); STAGE_B(T + 1, 0, 1, ns); }
    __builtin_amdgcn_s_setprio(1);
#pragma unroll
    for (int mt = 0; mt < 4; ++mt)
#pragma unroll
      for (int nt = 0; nt < 2; ++nt) {
        acc[mt][nt] = __builtin_amdgcn_mfma_f32_32x32x16_bf16(af[mt], b0[nt], acc[mt][nt], 0, 0, 0);
        acc[mt][nt] = __builtin_amdgcn_mfma_f32_32x32x16_bf16(ag[mt], b1[nt], acc[mt][nt], 0, 0, 0);
      }
    __builtin_amdgcn_s_setprio(0);
    __builtin_amdgcn_s_barrier();
    __builtin_amdgcn_sched_barrier(0);
    // ---- phase 2: ks 2,3 ----
#pragma unroll
    for (int nt = 0; nt < 2; ++nt) { b0[nt] = RD_B(nt, 2); b1[nt] = RD_B(nt, 3); }
#pragma unroll
    for (int mt = 0; mt < 4; ++mt) { af[mt] = RD_A(mt, 2); ag[mt] = RD_A(mt, 3); }
    if (pf) { STAGE_B(T + 1, 1, 0, ns); STAGE_B(T + 1, 1, 1, ns); }
    __builtin_amdgcn_s_setprio(1);
#pragma unroll
    for (int mt = 0; mt < 4; ++mt)
#pragma unroll
      for (int nt = 0; nt < 2; ++nt) {
        acc[mt][nt] = __builtin_amdgcn_mfma_f32_32x32x16_bf16(af[mt], b0[nt], acc[mt][nt], 0, 0, 0);
        acc[mt][nt] = __builtin_amdgcn_mfma_f32_32x32x16_bf16(ag[mt], b1[nt], acc[mt][nt], 0, 0, 0);
      }
    __builtin_amdgcn_s_setprio(0);
    __builtin_amdgcn_s_barrier();
    __builtin_amdgcn_sched_barrier(0);
  }
#undef STAGE_A
#undef STAGE_B
#undef RD_A
#undef RD_B

  // epilogue: per column-pair exp reduction. Lane covers col = kwc*64 + nt*32 + (l&31);
  // rows via 16 regs x lane-half; lane^32 has same col (other row half) -> xor32.
  float dpn[2] = {0.f, 0.f};
  float npn[2] = {0.f, 0.f};
#pragma unroll
  for (int nt = 0; nt < 2; ++nt) {
    const int col = n0 + kwc * 64 + nt * 32 + l31;
    const float bc = bkv[col];
#pragma unroll
    for (int mt = 0; mt < 4; ++mt)
#pragma unroll
      for (int r = 0; r < 16; ++r) {
        float x = acc[mt][nt][r] + bc;
        float xp = __shfl_xor(x, 1);  // partner column (V for even lanes)
        float e = __expf(x);
        dpn[nt] += e;
        npn[nt] += e * xp;
      }
    dpn[nt] += __shfl_xor(dpn[nt], 32);
    npn[nt] += __shfl_xor(npn[nt], 32);
  }
  if (l < 32 && (l & 1) == 0) {
#pragma unroll
    for (int nt = 0; nt < 2; ++nt) {
      sD[kwr][kwc * 32 + nt * 16 + (l >> 1)] = dpn[nt];
      sN[kwr][kwc * 32 + nt * 16 + (l >> 1)] = npn[nt];
    }
  }
  __syncthreads();
  if (tid < 128) {
    pden[(size_t)by * 1024 + bx * 128 + tid] = sD[0][tid] + sD[1][tid];
    pnum[(size_t)by * 1024 + bx * 128 + tid] = sN[0][tid] + sN[1][tid];
  }
}

// ======================= Q GEMM (8-wave, 32x32x16) + fused cval reduce ==========
// BM=256, BN=128, BK=64. grid 256, 8 waves as 4M x 2N; wave tile 64x64 = 2x2 frags.
// Epilogue: out = cval * sigmoid(acc + bq).
__global__ __launch_bounds__(512, 1) void gemm_q32(const bf16_t* __restrict__ A,
                                                   const bf16_t* __restrict__ Bq,
                                                   const float* __restrict__ bias,
                                                   const float* __restrict__ pden,
                                                   const float* __restrict__ pnum,
                                                   float* __restrict__ C) {
  __shared__ bf16_t lA[2 * 256 * 64];
  __shared__ bf16_t lB[2 * 128 * 64];
  __shared__ float red[512];

  const int tid = threadIdx.x;
  const int w = tid >> 6, l = tid & 63;
  const int qwr = w >> 1, qwc = w & 1;         // 4M x 2N waves
  const int swz = (blockIdx.x & 7) * 32 + (blockIdx.x >> 3);
  const int bx = swz & 7, by = swz >> 3;
  const int m0 = by * 256, n0 = bx * 128;

  const int rl3 = l >> 3;
  const int scol = ((l & 7) ^ rl3) * 8;
  const int l31 = l & 31, lhi = l >> 5, sw = l & 7;

  const bf16_t* Ab = A + (size_t)(m0 + w * 8 + rl3) * 1024 + scol;
  const bf16_t* Bb = Bq + (size_t)(n0 + w * 8 + rl3) * 1024 + scol;

  f32x16 acc[2][2];
#pragma unroll
  for (int m = 0; m < 2; ++m)
#pragma unroll
    for (int n = 0; n < 2; ++n) acc[m][n] = (f32x16){0.f};

#define STAGE_A(kt, h, r, slot)                                              \
  gload_lds16(Ab + (size_t)((h) * 128 + (r) * 64) * 1024 + (kt) * 64,        \
              &lA[(slot) * 16384 + ((h) * 128 + (r) * 64 + w * 8) * 64])
#define STAGE_B(kt, h, slot)                                                 \
  gload_lds16(Bb + (size_t)((h) * 64) * 1024 + (kt) * 64,                    \
              &lB[(slot) * 8192 + ((h) * 64 + w * 8) * 64])
#define RD_A(mt, ks) \
  (*reinterpret_cast<const bf16x8*>(&lA[slot * 16384 + (qwr * 64 + (mt) * 32 + l31) * 64 + ((((ks) * 2) + lhi) ^ sw) * 8]))
#define RD_B(nt, ks) \
  (*reinterpret_cast<const bf16x8*>(&lB[slot * 8192 + (qwc * 64 + (nt) * 32 + l31) * 64 + ((((ks) * 2) + lhi) ^ sw) * 8]))

  // prologue: tile 0 (6 loads) -- in flight while we reduce cval below
  STAGE_A(0, 0, 0, 0); STAGE_A(0, 0, 1, 0); STAGE_A(0, 1, 0, 0); STAGE_A(0, 1, 1, 0);
  STAGE_B(0, 0, 0); STAGE_B(0, 1, 0);

  // ---- fused finalize: cval = sum_col (sum_by pnum) / (sum_by pden) ----
  float vsum = 0.f;
#pragma unroll
  for (int j = 0; j < 2; ++j) {
    const int c = tid + j * 512;
    float d = 0.f, nm = 0.f;
#pragma unroll 8
    for (int b2 = 0; b2 < 32; ++b2) {
      d += pden[b2 * 1024 + c];
      nm += pnum[b2 * 1024 + c];
    }
    vsum += nm / d;
  }
  red[tid] = vsum;
  __syncthreads();
  for (int s = 256; s > 0; s >>= 1) {
    if (tid < s) red[tid] += red[tid + s];
    __syncthreads();
  }
  const float cv = red[0];
  // FIFO drain: the reduce's data-dependency waits retired the older tile-0 stages.

#pragma unroll 1
  for (int T = 0; T < NKT; ++T) {
    const int slot = T & 1, ns = slot ^ 1;
    const bool pf = (T + 1) < NKT;
    if (pf) { STAGE_A(T + 1, 0, 0, ns); STAGE_A(T + 1, 0, 1, ns); }
    if (pf) asm volatile("s_waitcnt vmcnt(2)" ::: "memory");
    else    asm volatile("s_waitcnt vmcnt(0)" ::: "memory");
    __builtin_amdgcn_s_barrier();
    __builtin_amdgcn_sched_barrier(0);

    bf16x8 af[2], ag[2], b0[2], b1[2];
    // ---- phase 1: ks 0,1 ----
#pragma unroll
    for (int nt = 0; nt < 2; ++nt) { b0[nt] = RD_B(nt, 0); b1[nt] = RD_B(nt, 1); }
#pragma unroll
    for (int mt = 0; mt < 2; ++mt) { af[mt] = RD_A(mt, 0); ag[mt] = RD_A(mt, 1); }
    if (pf) { STAGE_A(T + 1, 1, 0, ns); STAGE_A(T + 1, 1, 1, ns); STAGE_B(T + 1, 0, ns); }
    __builtin_amdgcn_s_setprio(1);
#pragma unroll
    for (int mt = 0; mt < 2; ++mt)
#pragma unroll
      for (int nt = 0; nt < 2; ++nt) {
        acc[mt][nt] = __builtin_amdgcn_mfma_f32_32x32x16_bf16(af[mt], b0[nt], acc[mt][nt], 0, 0, 0);
        acc[mt][nt] = __builtin_amdgcn_mfma_f32_32x32x16_bf16(ag[mt], b1[nt], acc[mt][nt], 0, 0, 0);
      }
    __builtin_amdgcn_s_setprio(0);
    __builtin_amdgcn_s_barrier();
    __builtin_amdgcn_sched_barrier(0);
    // ---- phase 2: ks 2,3 ----
#pragma unroll
    for (int nt = 0; nt < 2; ++nt) { b0[nt] = RD_B(nt, 2); b1[nt] = RD_B(nt, 3); }
#pragma unroll
    for (int mt = 0; mt < 2; ++mt) { af[mt] = RD_A(mt, 2); ag[mt] = RD_A(mt, 3); }
    if (pf) STAGE_B(T + 1, 1, ns);
    __builtin_amdgcn_s_setprio(1);
#pragma unroll
    for (int mt = 0; mt < 2; ++mt)
#pragma unroll
      for (int nt = 0; nt < 2; ++nt) {
        acc[mt][nt] = __builtin_amdgcn_mfma_f32_32x32x16_bf16(af[mt], b0[nt], acc[mt][nt], 0, 0, 0);
        acc[mt][nt] = __builtin_amdgcn_mfma_f32_32x32x16_bf16(ag[mt], b1[nt], acc[mt][nt], 0, 0, 0);
      }
    __builtin_amdgcn_s_setprio(0);
    __builtin_amdgcn_s_barrier();
    __builtin_amdgcn_sched_barrier(0);
  }
#undef STAGE_A
#undef STAGE_B
#undef RD_A
#undef RD_B

  // epilogue: col = n0 + qwc*64 + nt*32 + (l&31);
  // row = m0 + qwr*64 + mt*32 + (r&3) + 8*(r>>2) + 4*(l>>5)
#pragma unroll
  for (int nt = 0; nt < 2; ++nt) {
    const int col = n0 + qwc * 64 + nt * 32 + l31;
    const float bs = bias[col];
#pragma unroll
    for (int mt = 0; mt < 2; ++mt) {
      const int rbase = m0 + qwr * 64 + mt * 32 + 4 * lhi;
#pragma unroll
      for (int r = 0; r < 16; ++r) {
        const int row = rbase + (r & 3) + 8 * (r >> 2);
        float v = acc[mt][nt][r] + bs;
        v = cv / (1.f + __expf(-v));
        C[(size_t)row * 1024 + col] = v;
      }
    }
  }
}

extern "C" void kernel_launch(void* const* d_in, const int* in_sizes, int n_in,
                              void* d_out, int out_size, void* d_ws, size_t ws_size,
                              hipStream_t stream) {
  const float* q = (const float*)d_in[0];
  const float* Wq = (const float*)d_in[1];
  const float* bq = (const float*)d_in[2];
  const float* Wk = (const float*)d_in[3];
  const float* bk = (const float*)d_in[4];
  const float* Wv = (const float*)d_in[5];
  const float* bv = (const float*)d_in[6];
  float* out = (float*)d_out;

  char* ws = (char*)d_ws;
  bf16_t* qb = (bf16_t*)ws;                                  // 16 MB
  bf16_t* Wkv = (bf16_t*)(ws + (size_t)16 * 1024 * 1024);    // 4 MB interleaved
  bf16_t* Wqb = (bf16_t*)(ws + (size_t)20 * 1024 * 1024);    // 2 MB
  float* bkv = (float*)(ws + (size_t)22 * 1024 * 1024);      // 8 KB
  float* pden = (float*)(ws + (size_t)23 * 1024 * 1024);     // 128 KB
  float* pnum = (float*)(ws + (size_t)23 * 1024 * 1024 + 131072);

  cvt_all<<<5633, 256, 0, stream>>>(q, Wk, Wv, Wq, bk, bv, qb, Wkv, Wqb, bkv);
  gemm_kv32<<<256, 512, 0, stream>>>(qb, Wkv, bkv, pden, pnum);
  gemm_q32<<<256, 512, 0, stream>>>(qb, Wqb, bq, pden, pnum, out);
}

// Round 10
// 77.726 us; speedup vs baseline: 1.0750x; 1.0750x over previous
//
#include <hip/hip_runtime.h>
#include <hip/hip_bf16.h>
#include <stdint.h>

typedef __bf16 bf16_t;
typedef __bf16 bf16x8 __attribute__((ext_vector_type(8)));
typedef float f32x4 __attribute__((ext_vector_type(4)));

#define NKT 16  // K-tiles: 1024 / 64

// ---- global -> LDS direct load, 16 B per lane (dest = wave-uniform base + lane*16) ----
__device__ __forceinline__ void gload_lds16(const void* g, void* l) {
  using gptr_t = const __attribute__((address_space(1))) void*;
  using lptr_t = __attribute__((address_space(3))) void*;
  gptr_t gp = (gptr_t)(uintptr_t)g;
  lptr_t lp = (lptr_t)(uint32_t)(uintptr_t)l;
  __builtin_amdgcn_global_load_lds(gp, lp, 16, 0, 0);
}

__device__ __forceinline__ bf16x8 cvt8v(const float* __restrict__ src, int i8) {
  const float4* s = reinterpret_cast<const float4*>(src) + (size_t)i8 * 2;
  float4 a = s[0], b = s[1];
  bf16x8 o;
  o[0] = (bf16_t)a.x; o[1] = (bf16_t)a.y; o[2] = (bf16_t)a.z; o[3] = (bf16_t)a.w;
  o[4] = (bf16_t)b.x; o[5] = (bf16_t)b.y; o[6] = (bf16_t)b.z; o[7] = (bf16_t)b.w;
  return o;
}

// converts q->qb, Wk/Wv -> interleaved Wkv (row 2j = Wk_j, 2j+1 = Wv_j), Wq->Wqb, bk/bv->bkv
__global__ __launch_bounds__(256) void cvt_all(const float* __restrict__ q,
                                               const float* __restrict__ Wk,
                                               const float* __restrict__ Wv,
                                               const float* __restrict__ Wq,
                                               const float* __restrict__ bk,
                                               const float* __restrict__ bv,
                                               bf16_t* __restrict__ qb,
                                               bf16_t* __restrict__ Wkv,
                                               bf16_t* __restrict__ Wqb,
                                               float* __restrict__ bkv) {
  const int b = blockIdx.x;
  const int t = threadIdx.x;
  if (b < 4096) {
    int i = b * 256 + t;
    *reinterpret_cast<bf16x8*>(qb + (size_t)i * 8) = cvt8v(q, i);
  } else if (b < 4608) {
    int i = (b - 4096) * 256 + t;
    int j = i >> 7, c8 = i & 127;
    *reinterpret_cast<bf16x8*>(Wkv + (size_t)j * 2048 + c8 * 8) = cvt8v(Wk, i);
  } else if (b < 5120) {
    int i = (b - 4608) * 256 + t;
    int j = i >> 7, c8 = i & 127;
    *reinterpret_cast<bf16x8*>(Wkv + (size_t)j * 2048 + 1024 + c8 * 8) = cvt8v(Wv, i);
  } else if (b < 5632) {
    int i = (b - 5120) * 256 + t;
    *reinterpret_cast<bf16x8*>(Wqb + (size_t)i * 8) = cvt8v(Wq, i);
  } else {
#pragma unroll
    for (int u = 0; u < 4; ++u) {
      int j = t * 4 + u;
      bkv[2 * j] = bk[j];
      bkv[2 * j + 1] = bv[j];
    }
  }
}

// ======================= fused KV GEMM (8-wave, counted-vmcnt) — R7 exact ============
// A: qb [8192][1024], Bkv: interleaved [2048][1024]. BM=256, BN=256, BK=64.
// grid 256 (32 m x 8 n), 512 threads = 8 waves (2M x 4N).
// Epilogue: column-pair exp-reduction -> pden/pnum[32][1024].
__global__ __launch_bounds__(512, 1) void gemm_kv8(const bf16_t* __restrict__ A,
                                                   const bf16_t* __restrict__ Bkv,
                                                   const float* __restrict__ bkv,
                                                   float* __restrict__ pden,
                                                   float* __restrict__ pnum) {
  __shared__ bf16_t lA[2 * 256 * 64];
  __shared__ bf16_t lB[2 * 256 * 64];
  __shared__ float sD[2][128];
  __shared__ float sN[2][128];

  const int tid = threadIdx.x;
  const int w = tid >> 6, l = tid & 63;
  const int wr = w >> 2, wc = w & 3;           // 2M x 4N waves
  const int swz = (blockIdx.x & 7) * 32 + (blockIdx.x >> 3);  // XCD chunking (256%8==0)
  const int bx = swz & 7, by = swz >> 3;
  const int m0 = by * 256, n0 = bx * 256;

  const int rl3 = l >> 3;
  const int scol = ((l & 7) ^ rl3) * 8;        // pre-swizzled global source chunk
  const int fr = l & 15, fg = l >> 4, sw = l & 7;

  const bf16_t* Ab = A + (size_t)(m0 + w * 8 + rl3) * 1024 + scol;
  const bf16_t* Bb = Bkv + (size_t)(n0 + w * 8 + rl3) * 1024 + scol;

  f32x4 acc[8][4];
#pragma unroll
  for (int m = 0; m < 8; ++m)
#pragma unroll
    for (int n = 0; n < 4; ++n) acc[m][n] = (f32x4){0.f, 0.f, 0.f, 0.f};

#define STAGE_A(kt, h, r, slot)                                              \
  gload_lds16(Ab + (size_t)((h) * 128 + (r) * 64) * 1024 + (kt) * 64,        \
              &lA[(slot) * 16384 + ((h) * 128 + (r) * 64 + w * 8) * 64])
#define STAGE_B(kt, h, r, slot)                                              \
  gload_lds16(Bb + (size_t)((h) * 128 + (r) * 64) * 1024 + (kt) * 64,        \
              &lB[(slot) * 16384 + ((h) * 128 + (r) * 64 + w * 8) * 64])
#define RD_A(mm, ks) \
  (*reinterpret_cast<const bf16x8*>(&lA[aBase + ((mm) * 16 + fr) * 64 + ((((ks) * 4) + fg) ^ sw) * 8]))
#define RD_B(nn, ks) \
  (*reinterpret_cast<const bf16x8*>(&lB[bBase + ((nn) * 16 + fr) * 64 + ((((ks) * 4) + fg) ^ sw) * 8]))

  STAGE_A(0, 0, 0, 0); STAGE_A(0, 0, 1, 0); STAGE_A(0, 1, 0, 0); STAGE_A(0, 1, 1, 0);
  STAGE_B(0, 0, 0, 0); STAGE_B(0, 0, 1, 0); STAGE_B(0, 1, 0, 0); STAGE_B(0, 1, 1, 0);

#pragma unroll 1
  for (int T = 0; T < NKT; ++T) {
    const int slot = T & 1, ns = slot ^ 1;
    const bool pf = (T + 1) < NKT;
    if (pf) { STAGE_A(T + 1, 0, 0, ns); STAGE_A(T + 1, 0, 1, ns); }
    if (pf) asm volatile("s_waitcnt vmcnt(2)" ::: "memory");
    else    asm volatile("s_waitcnt vmcnt(0)" ::: "memory");
    __builtin_amdgcn_s_barrier();
    __builtin_amdgcn_sched_barrier(0);

    const int aBase = slot * 16384 + wr * 8192;
    const int bBase = slot * 16384 + wc * 4096;
    bf16x8 af[4], bfv[4];
    // phase 1: ks=0, m 0..3
#pragma unroll
    for (int n = 0; n < 4; ++n) bfv[n] = RD_B(n, 0);
#pragma unroll
    for (int m = 0; m < 4; ++m) af[m] = RD_A(m, 0);
    if (pf) { STAGE_A(T + 1, 1, 0, ns); STAGE_A(T + 1, 1, 1, ns); }
    __builtin_amdgcn_s_setprio(1);
#pragma unroll
    for (int m = 0; m < 4; ++m)
#pragma unroll
      for (int n = 0; n < 4; ++n)
        acc[m][n] = __builtin_amdgcn_mfma_f32_16x16x32_bf16(af[m], bfv[n], acc[m][n], 0, 0, 0);
    __builtin_amdgcn_s_setprio(0);
    __builtin_amdgcn_s_barrier();
    __builtin_amdgcn_sched_barrier(0);
    // phase 2: ks=0, m 4..7
#pragma unroll
    for (int m = 0; m < 4; ++m) af[m] = RD_A(m + 4, 0);
    if (pf) { STAGE_B(T + 1, 0, 0, ns); STAGE_B(T + 1, 0, 1, ns); }
    __builtin_amdgcn_s_setprio(1);
#pragma unroll
    for (int m = 0; m < 4; ++m)
#pragma unroll
      for (int n = 0; n < 4; ++n)
        acc[m + 4][n] = __builtin_amdgcn_mfma_f32_16x16x32_bf16(af[m], bfv[n], acc[m + 4][n], 0, 0, 0);
    __builtin_amdgcn_s_setprio(0);
    __builtin_amdgcn_s_barrier();
    __builtin_amdgcn_sched_barrier(0);
    // phase 3: ks=1, m 0..3
#pragma unroll
    for (int n = 0; n < 4; ++n) bfv[n] = RD_B(n, 1);
#pragma unroll
    for (int m = 0; m < 4; ++m) af[m] = RD_A(m, 1);
    if (pf) { STAGE_B(T + 1, 1, 0, ns); STAGE_B(T + 1, 1, 1, ns); }
    __builtin_amdgcn_s_setprio(1);
#pragma unroll
    for (int m = 0; m < 4; ++m)
#pragma unroll
      for (int n = 0; n < 4; ++n)
        acc[m][n] = __builtin_amdgcn_mfma_f32_16x16x32_bf16(af[m], bfv[n], acc[m][n], 0, 0, 0);
    __builtin_amdgcn_s_setprio(0);
    __builtin_amdgcn_s_barrier();
    __builtin_amdgcn_sched_barrier(0);
    // phase 4: ks=1, m 4..7
#pragma unroll
    for (int m = 0; m < 4; ++m) af[m] = RD_A(m + 4, 1);
    __builtin_amdgcn_s_setprio(1);
#pragma unroll
    for (int m = 0; m < 4; ++m)
#pragma unroll
      for (int n = 0; n < 4; ++n)
        acc[m + 4][n] = __builtin_amdgcn_mfma_f32_16x16x32_bf16(af[m], bfv[n], acc[m + 4][n], 0, 0, 0);
    __builtin_amdgcn_s_setprio(0);
    __builtin_amdgcn_s_barrier();
    __builtin_amdgcn_sched_barrier(0);
  }
#undef STAGE_A
#undef STAGE_B
#undef RD_A
#undef RD_B

  // epilogue: per column-pair exp reduction over this block's 256 rows
  float dpn[4] = {0.f, 0.f, 0.f, 0.f};
  float npn[4] = {0.f, 0.f, 0.f, 0.f};
#pragma unroll
  for (int n = 0; n < 4; ++n) {
    const int col = n0 + wc * 64 + n * 16 + fr;
    const float bc = bkv[col];
#pragma unroll
    for (int m = 0; m < 8; ++m)
#pragma unroll
      for (int r = 0; r < 4; ++r) {
        float x = acc[m][n][r] + bc;
        float xp = __shfl_xor(x, 1);  // partner column (V for even lanes)
        float e = __expf(x);
        dpn[n] += e;
        npn[n] += e * xp;
      }
    dpn[n] += __shfl_xor(dpn[n], 16); dpn[n] += __shfl_xor(dpn[n], 32);
    npn[n] += __shfl_xor(npn[n], 16); npn[n] += __shfl_xor(npn[n], 32);
  }
  if (l < 16 && (l & 1) == 0) {
#pragma unroll
    for (int n = 0; n < 4; ++n) {
      sD[wr][wc * 32 + n * 8 + (l >> 1)] = dpn[n];
      sN[wr][wc * 32 + n * 8 + (l >> 1)] = npn[n];
    }
  }
  __syncthreads();
  if (tid < 128) {
    pden[(size_t)by * 1024 + bx * 128 + tid] = sD[0][tid] + sD[1][tid];
    pnum[(size_t)by * 1024 + bx * 128 + tid] = sN[0][tid] + sN[1][tid];
  }
}

// ======================= Q GEMM (8-wave, 2-phase/tile) + fused cval reduce ==========
// BM=256, BN=128, BK=64. grid 256 (32 m x 8 n), 8 waves as 4M x 2N.
// 2 phases/K-tile (ks=0: 16 MFMA, ks=1: 16 MFMA) -> 3 barriers/tile (vs 5 in R7),
// raising MFMA-per-barrier from 6.4 to 10.7 (kv8-level). Reads keep the proven
// conflict-free (ks*4+fg)^sw pattern. Stages {3 entry, 3 in p1}, vmcnt(3).
// Epilogue: out = cval * sigmoid(acc + bq).
__global__ __launch_bounds__(512, 1) void gemm_q8(const bf16_t* __restrict__ A,
                                                  const bf16_t* __restrict__ Bq,
                                                  const float* __restrict__ bias,
                                                  const float* __restrict__ pden,
                                                  const float* __restrict__ pnum,
                                                  float* __restrict__ C) {
  __shared__ bf16_t lA[2 * 256 * 64];
  __shared__ bf16_t lB[2 * 128 * 64];
  __shared__ float red[512];

  const int tid = threadIdx.x;
  const int w = tid >> 6, l = tid & 63;
  const int wr = w >> 1, wc = w & 1;           // 4M x 2N waves
  const int swz = (blockIdx.x & 7) * 32 + (blockIdx.x >> 3);
  const int bx = swz & 7, by = swz >> 3;
  const int m0 = by * 256, n0 = bx * 128;

  const int rl3 = l >> 3;
  const int scol = ((l & 7) ^ rl3) * 8;
  const int fr = l & 15, fg = l >> 4, sw = l & 7;

  const bf16_t* Ab = A + (size_t)(m0 + w * 8 + rl3) * 1024 + scol;
  const bf16_t* Bb = Bq + (size_t)(n0 + w * 8 + rl3) * 1024 + scol;

  f32x4 acc[4][4];
#pragma unroll
  for (int m = 0; m < 4; ++m)
#pragma unroll
    for (int n = 0; n < 4; ++n) acc[m][n] = (f32x4){0.f, 0.f, 0.f, 0.f};

#define STAGE_A(kt, h, r, slot)                                              \
  gload_lds16(Ab + (size_t)((h) * 128 + (r) * 64) * 1024 + (kt) * 64,        \
              &lA[(slot) * 16384 + ((h) * 128 + (r) * 64 + w * 8) * 64])
#define STAGE_B(kt, h, slot)                                                 \
  gload_lds16(Bb + (size_t)((h) * 64) * 1024 + (kt) * 64,                    \
              &lB[(slot) * 8192 + ((h) * 64 + w * 8) * 64])
#define RD_A(mm, ks) \
  (*reinterpret_cast<const bf16x8*>(&lA[aBase + ((mm) * 16 + fr) * 64 + ((((ks) * 4) + fg) ^ sw) * 8]))
#define RD_B(nn, ks) \
  (*reinterpret_cast<const bf16x8*>(&lB[bBase + ((nn) * 16 + fr) * 64 + ((((ks) * 4) + fg) ^ sw) * 8]))

  // prologue: tile 0 (6 loads) -- in flight while we reduce cval below
  STAGE_A(0, 0, 0, 0); STAGE_A(0, 0, 1, 0); STAGE_A(0, 1, 0, 0); STAGE_A(0, 1, 1, 0);
  STAGE_B(0, 0, 0); STAGE_B(0, 1, 0);

  // ---- fused finalize: cval = sum_col (sum_by pnum) / (sum_by pden) ----
  float vsum = 0.f;
#pragma unroll
  for (int j = 0; j < 2; ++j) {
    const int c = tid + j * 512;
    float d = 0.f, nm = 0.f;
#pragma unroll 8
    for (int b2 = 0; b2 < 32; ++b2) {
      d += pden[b2 * 1024 + c];
      nm += pnum[b2 * 1024 + c];
    }
    vsum += nm / d;
  }
  red[tid] = vsum;
  __syncthreads();
  for (int s = 256; s > 0; s >>= 1) {
    if (tid < s) red[tid] += red[tid + s];
    __syncthreads();
  }
  const float cv = red[0];
  // note: the reduce's __syncthreads drained vmcnt -> tile-0 stages landed.

#pragma unroll 1
  for (int T = 0; T < NKT; ++T) {
    const int slot = T & 1, ns = slot ^ 1;
    const bool pf = (T + 1) < NKT;
    // entry: first half of next tile's stages (2A + 1B)
    if (pf) { STAGE_A(T + 1, 0, 0, ns); STAGE_A(T + 1, 0, 1, ns); STAGE_B(T + 1, 0, ns); }
    if (pf) asm volatile("s_waitcnt vmcnt(3)" ::: "memory");
    else    asm volatile("s_waitcnt vmcnt(0)" ::: "memory");
    __builtin_amdgcn_s_barrier();
    __builtin_amdgcn_sched_barrier(0);

    const int aBase = slot * 16384 + wr * 4096;
    const int bBase = slot * 8192 + wc * 4096;
    bf16x8 af[4], bfv[4];
    // ---- phase 1: ks=0, all m 0..3 (16 MFMA) + second half of stages ----
#pragma unroll
    for (int n = 0; n < 4; ++n) bfv[n] = RD_B(n, 0);
#pragma unroll
    for (int m = 0; m < 4; ++m) af[m] = RD_A(m, 0);
    if (pf) { STAGE_A(T + 1, 1, 0, ns); STAGE_A(T + 1, 1, 1, ns); STAGE_B(T + 1, 1, ns); }
    __builtin_amdgcn_s_setprio(1);
#pragma unroll
    for (int m = 0; m < 4; ++m)
#pragma unroll
      for (int n = 0; n < 4; ++n)
        acc[m][n] = __builtin_amdgcn_mfma_f32_16x16x32_bf16(af[m], bfv[n], acc[m][n], 0, 0, 0);
    __builtin_amdgcn_s_setprio(0);
    __builtin_amdgcn_s_barrier();
    __builtin_amdgcn_sched_barrier(0);
    // ---- phase 2: ks=1, all m 0..3 (16 MFMA) ----
#pragma unroll
    for (int n = 0; n < 4; ++n) bfv[n] = RD_B(n, 1);
#pragma unroll
    for (int m = 0; m < 4; ++m) af[m] = RD_A(m, 1);
    __builtin_amdgcn_s_setprio(1);
#pragma unroll
    for (int m = 0; m < 4; ++m)
#pragma unroll
      for (int n = 0; n < 4; ++n)
        acc[m][n] = __builtin_amdgcn_mfma_f32_16x16x32_bf16(af[m], bfv[n], acc[m][n], 0, 0, 0);
    __builtin_amdgcn_s_setprio(0);
    __builtin_amdgcn_s_barrier();
    __builtin_amdgcn_sched_barrier(0);
  }
#undef STAGE_A
#undef STAGE_B
#undef RD_A
#undef RD_B

#pragma unroll
  for (int n = 0; n < 4; ++n) {
    const int col = n0 + wc * 64 + n * 16 + fr;
    const float bs = bias[col];
#pragma unroll
    for (int m = 0; m < 4; ++m) {
      const int row = m0 + wr * 64 + m * 16 + fg * 4;
#pragma unroll
      for (int r = 0; r < 4; ++r) {
        float v = acc[m][n][r] + bs;
        v = cv / (1.f + __expf(-v));
        C[(size_t)(row + r) * 1024 + col] = v;
      }
    }
  }
}

extern "C" void kernel_launch(void* const* d_in, const int* in_sizes, int n_in,
                              void* d_out, int out_size, void* d_ws, size_t ws_size,
                              hipStream_t stream) {
  const float* q = (const float*)d_in[0];
  const float* Wq = (const float*)d_in[1];
  const float* bq = (const float*)d_in[2];
  const float* Wk = (const float*)d_in[3];
  const float* bk = (const float*)d_in[4];
  const float* Wv = (const float*)d_in[5];
  const float* bv = (const float*)d_in[6];
  float* out = (float*)d_out;

  char* ws = (char*)d_ws;
  bf16_t* qb = (bf16_t*)ws;                                  // 16 MB
  bf16_t* Wkv = (bf16_t*)(ws + (size_t)16 * 1024 * 1024);    // 4 MB interleaved
  bf16_t* Wqb = (bf16_t*)(ws + (size_t)20 * 1024 * 1024);    // 2 MB
  float* bkv = (float*)(ws + (size_t)22 * 1024 * 1024);      // 8 KB
  float* pden = (float*)(ws + (size_t)23 * 1024 * 1024);     // 128 KB
  float* pnum = (float*)(ws + (size_t)23 * 1024 * 1024 + 131072);

  cvt_all<<<5633, 256, 0, stream>>>(q, Wk, Wv, Wq, bk, bv, qb, Wkv, Wqb, bkv);
  gemm_kv8<<<256, 512, 0, stream>>>(qb, Wkv, bkv, pden, pnum);
  gemm_q8<<<256, 512, 0, stream>>>(qb, Wqb, bq, pden, pnum, out);
}

// Round 11
// 77.384 us; speedup vs baseline: 1.0798x; 1.0044x over previous
//
#include <hip/hip_runtime.h>
#include <hip/hip_bf16.h>
#include <stdint.h>

typedef __bf16 bf16_t;
typedef __bf16 bf16x8 __attribute__((ext_vector_type(8)));
typedef float f32x4 __attribute__((ext_vector_type(4)));

#define NKT 16  // K-tiles: 1024 / 64

// ---- global -> LDS direct load, 16 B per lane (dest = wave-uniform base + lane*16) ----
__device__ __forceinline__ void gload_lds16(const void* g, void* l) {
  using gptr_t = const __attribute__((address_space(1))) void*;
  using lptr_t = __attribute__((address_space(3))) void*;
  gptr_t gp = (gptr_t)(uintptr_t)g;
  lptr_t lp = (lptr_t)(uint32_t)(uintptr_t)l;
  __builtin_amdgcn_global_load_lds(gp, lp, 16, 0, 0);
}

__device__ __forceinline__ bf16x8 cvt8v(const float* __restrict__ src, int i8) {
  const float4* s = reinterpret_cast<const float4*>(src) + (size_t)i8 * 2;
  float4 a = s[0], b = s[1];
  bf16x8 o;
  o[0] = (bf16_t)a.x; o[1] = (bf16_t)a.y; o[2] = (bf16_t)a.z; o[3] = (bf16_t)a.w;
  o[4] = (bf16_t)b.x; o[5] = (bf16_t)b.y; o[6] = (bf16_t)b.z; o[7] = (bf16_t)b.w;
  return o;
}

// converts q->qb, Wk/Wv -> interleaved Wkv (row 2j = Wk_j, 2j+1 = Wv_j), Wq->Wqb, bk/bv->bkv
__global__ __launch_bounds__(256) void cvt_all(const float* __restrict__ q,
                                               const float* __restrict__ Wk,
                                               const float* __restrict__ Wv,
                                               const float* __restrict__ Wq,
                                               const float* __restrict__ bk,
                                               const float* __restrict__ bv,
                                               bf16_t* __restrict__ qb,
                                               bf16_t* __restrict__ Wkv,
                                               bf16_t* __restrict__ Wqb,
                                               float* __restrict__ bkv) {
  const int b = blockIdx.x;
  const int t = threadIdx.x;
  if (b < 4096) {
    int i = b * 256 + t;
    *reinterpret_cast<bf16x8*>(qb + (size_t)i * 8) = cvt8v(q, i);
  } else if (b < 4608) {
    int i = (b - 4096) * 256 + t;
    int j = i >> 7, c8 = i & 127;
    *reinterpret_cast<bf16x8*>(Wkv + (size_t)j * 2048 + c8 * 8) = cvt8v(Wk, i);
  } else if (b < 5120) {
    int i = (b - 4608) * 256 + t;
    int j = i >> 7, c8 = i & 127;
    *reinterpret_cast<bf16x8*>(Wkv + (size_t)j * 2048 + 1024 + c8 * 8) = cvt8v(Wv, i);
  } else if (b < 5632) {
    int i = (b - 5120) * 256 + t;
    *reinterpret_cast<bf16x8*>(Wqb + (size_t)i * 8) = cvt8v(Wq, i);
  } else {
#pragma unroll
    for (int u = 0; u < 4; ++u) {
      int j = t * 4 + u;
      bkv[2 * j] = bk[j];
      bkv[2 * j + 1] = bv[j];
    }
  }
}

// ======================= fused KV GEMM (8-wave, counted-vmcnt) =======================
// A: qb [8192][1024], Bkv: interleaved [2048][1024]. BM=256, BN=256, BK=64.
// grid 256 (32 m x 8 n), 512 threads = 8 waves (2M x 4N).
// Epilogue: column-pair exp-reduction -> pden/pnum[32][1024].
__global__ __launch_bounds__(512, 1) void gemm_kv8(const bf16_t* __restrict__ A,
                                                   const bf16_t* __restrict__ Bkv,
                                                   const float* __restrict__ bkv,
                                                   float* __restrict__ pden,
                                                   float* __restrict__ pnum) {
  __shared__ bf16_t lA[2 * 256 * 64];
  __shared__ bf16_t lB[2 * 256 * 64];
  __shared__ float sD[2][128];
  __shared__ float sN[2][128];

  const int tid = threadIdx.x;
  const int w = tid >> 6, l = tid & 63;
  const int wr = w >> 2, wc = w & 3;           // 2M x 4N waves
  const int swz = (blockIdx.x & 7) * 32 + (blockIdx.x >> 3);  // XCD chunking (256%8==0)
  const int bx = swz & 7, by = swz >> 3;
  const int m0 = by * 256, n0 = bx * 256;

  const int rl3 = l >> 3;
  const int scol = ((l & 7) ^ rl3) * 8;        // pre-swizzled global source chunk
  const int fr = l & 15, fg = l >> 4, sw = l & 7;

  const bf16_t* Ab = A + (size_t)(m0 + w * 8 + rl3) * 1024 + scol;
  const bf16_t* Bb = Bkv + (size_t)(n0 + w * 8 + rl3) * 1024 + scol;

  f32x4 acc[8][4];
#pragma unroll
  for (int m = 0; m < 8; ++m)
#pragma unroll
    for (int n = 0; n < 4; ++n) acc[m][n] = (f32x4){0.f, 0.f, 0.f, 0.f};

#define STAGE_A(kt, h, r, slot)                                              \
  gload_lds16(Ab + (size_t)((h) * 128 + (r) * 64) * 1024 + (kt) * 64,        \
              &lA[(slot) * 16384 + ((h) * 128 + (r) * 64 + w * 8) * 64])
#define STAGE_B(kt, h, r, slot)                                              \
  gload_lds16(Bb + (size_t)((h) * 128 + (r) * 64) * 1024 + (kt) * 64,        \
              &lB[(slot) * 16384 + ((h) * 128 + (r) * 64 + w * 8) * 64])
#define RD_A(mm, ks) \
  (*reinterpret_cast<const bf16x8*>(&lA[aBase + ((mm) * 16 + fr) * 64 + ((((ks) * 4) + fg) ^ sw) * 8]))
#define RD_B(nn, ks) \
  (*reinterpret_cast<const bf16x8*>(&lB[bBase + ((nn) * 16 + fr) * 64 + ((((ks) * 4) + fg) ^ sw) * 8]))

  STAGE_A(0, 0, 0, 0); STAGE_A(0, 0, 1, 0); STAGE_A(0, 1, 0, 0); STAGE_A(0, 1, 1, 0);
  STAGE_B(0, 0, 0, 0); STAGE_B(0, 0, 1, 0); STAGE_B(0, 1, 0, 0); STAGE_B(0, 1, 1, 0);

#pragma unroll 1
  for (int T = 0; T < NKT; ++T) {
    const int slot = T & 1, ns = slot ^ 1;
    const bool pf = (T + 1) < NKT;
    if (pf) { STAGE_A(T + 1, 0, 0, ns); STAGE_A(T + 1, 0, 1, ns); }
    if (pf) asm volatile("s_waitcnt vmcnt(2)" ::: "memory");
    else    asm volatile("s_waitcnt vmcnt(0)" ::: "memory");
    __builtin_amdgcn_s_barrier();
    __builtin_amdgcn_sched_barrier(0);

    const int aBase = slot * 16384 + wr * 8192;
    const int bBase = slot * 16384 + wc * 4096;
    bf16x8 af[4], bfv[4];
    // phase 1: ks=0, m 0..3
#pragma unroll
    for (int n = 0; n < 4; ++n) bfv[n] = RD_B(n, 0);
#pragma unroll
    for (int m = 0; m < 4; ++m) af[m] = RD_A(m, 0);
    if (pf) { STAGE_A(T + 1, 1, 0, ns); STAGE_A(T + 1, 1, 1, ns); }
    __builtin_amdgcn_s_setprio(1);
#pragma unroll
    for (int m = 0; m < 4; ++m)
#pragma unroll
      for (int n = 0; n < 4; ++n)
        acc[m][n] = __builtin_amdgcn_mfma_f32_16x16x32_bf16(af[m], bfv[n], acc[m][n], 0, 0, 0);
    __builtin_amdgcn_s_setprio(0);
    __builtin_amdgcn_s_barrier();
    __builtin_amdgcn_sched_barrier(0);
    // phase 2: ks=0, m 4..7
#pragma unroll
    for (int m = 0; m < 4; ++m) af[m] = RD_A(m + 4, 0);
    if (pf) { STAGE_B(T + 1, 0, 0, ns); STAGE_B(T + 1, 0, 1, ns); }
    __builtin_amdgcn_s_setprio(1);
#pragma unroll
    for (int m = 0; m < 4; ++m)
#pragma unroll
      for (int n = 0; n < 4; ++n)
        acc[m + 4][n] = __builtin_amdgcn_mfma_f32_16x16x32_bf16(af[m], bfv[n], acc[m + 4][n], 0, 0, 0);
    __builtin_amdgcn_s_setprio(0);
    __builtin_amdgcn_s_barrier();
    __builtin_amdgcn_sched_barrier(0);
    // phase 3: ks=1, m 0..3
#pragma unroll
    for (int n = 0; n < 4; ++n) bfv[n] = RD_B(n, 1);
#pragma unroll
    for (int m = 0; m < 4; ++m) af[m] = RD_A(m, 1);
    if (pf) { STAGE_B(T + 1, 1, 0, ns); STAGE_B(T + 1, 1, 1, ns); }
    __builtin_amdgcn_s_setprio(1);
#pragma unroll
    for (int m = 0; m < 4; ++m)
#pragma unroll
      for (int n = 0; n < 4; ++n)
        acc[m][n] = __builtin_amdgcn_mfma_f32_16x16x32_bf16(af[m], bfv[n], acc[m][n], 0, 0, 0);
    __builtin_amdgcn_s_setprio(0);
    __builtin_amdgcn_s_barrier();
    __builtin_amdgcn_sched_barrier(0);
    // phase 4: ks=1, m 4..7
#pragma unroll
    for (int m = 0; m < 4; ++m) af[m] = RD_A(m + 4, 1);
    __builtin_amdgcn_s_setprio(1);
#pragma unroll
    for (int m = 0; m < 4; ++m)
#pragma unroll
      for (int n = 0; n < 4; ++n)
        acc[m + 4][n] = __builtin_amdgcn_mfma_f32_16x16x32_bf16(af[m], bfv[n], acc[m + 4][n], 0, 0, 0);
    __builtin_amdgcn_s_setprio(0);
    __builtin_amdgcn_s_barrier();
    __builtin_amdgcn_sched_barrier(0);
  }
#undef STAGE_A
#undef STAGE_B
#undef RD_A
#undef RD_B

  // epilogue: per column-pair exp reduction over this block's 256 rows
  float dpn[4] = {0.f, 0.f, 0.f, 0.f};
  float npn[4] = {0.f, 0.f, 0.f, 0.f};
#pragma unroll
  for (int n = 0; n < 4; ++n) {
    const int col = n0 + wc * 64 + n * 16 + fr;
    const float bc = bkv[col];
#pragma unroll
    for (int m = 0; m < 8; ++m)
#pragma unroll
      for (int r = 0; r < 4; ++r) {
        float x = acc[m][n][r] + bc;
        float xp = __shfl_xor(x, 1);  // partner column (V for even lanes)
        float e = __expf(x);
        dpn[n] += e;
        npn[n] += e * xp;
      }
    dpn[n] += __shfl_xor(dpn[n], 16); dpn[n] += __shfl_xor(dpn[n], 32);
    npn[n] += __shfl_xor(npn[n], 16); npn[n] += __shfl_xor(npn[n], 32);
  }
  if (l < 16 && (l & 1) == 0) {
#pragma unroll
    for (int n = 0; n < 4; ++n) {
      sD[wr][wc * 32 + n * 8 + (l >> 1)] = dpn[n];
      sN[wr][wc * 32 + n * 8 + (l >> 1)] = npn[n];
    }
  }
  __syncthreads();
  if (tid < 128) {
    pden[(size_t)by * 1024 + bx * 128 + tid] = sD[0][tid] + sD[1][tid];
    pnum[(size_t)by * 1024 + bx * 128 + tid] = sN[0][tid] + sN[1][tid];
  }
}

// ======================= Q GEMM (8-wave, counted-vmcnt) + fused cval reduce ==========
// BM=256, BN=128, BK=64. grid 256 (32 m x 8 n), 8 waves as 4M x 2N.
// Prologue: issue tile-0 stages, then compute cval from pden/pnum (kv8 completed:
// stream order guarantees visibility; the reduce hides the DMA latency).
// Epilogue: out = cval * sigmoid(acc + bq).
__global__ __launch_bounds__(512, 1) void gemm_q8(const bf16_t* __restrict__ A,
                                                  const bf16_t* __restrict__ Bq,
                                                  const float* __restrict__ bias,
                                                  const float* __restrict__ pden,
                                                  const float* __restrict__ pnum,
                                                  float* __restrict__ C) {
  __shared__ bf16_t lA[2 * 256 * 64];
  __shared__ bf16_t lB[2 * 128 * 64];
  __shared__ float red[512];

  const int tid = threadIdx.x;
  const int w = tid >> 6, l = tid & 63;
  const int wr = w >> 1, wc = w & 1;           // 4M x 2N waves
  const int swz = (blockIdx.x & 7) * 32 + (blockIdx.x >> 3);
  const int bx = swz & 7, by = swz >> 3;
  const int m0 = by * 256, n0 = bx * 128;

  const int rl3 = l >> 3;
  const int scol = ((l & 7) ^ rl3) * 8;
  const int fr = l & 15, fg = l >> 4, sw = l & 7;

  const bf16_t* Ab = A + (size_t)(m0 + w * 8 + rl3) * 1024 + scol;
  const bf16_t* Bb = Bq + (size_t)(n0 + w * 8 + rl3) * 1024 + scol;

  f32x4 acc[4][4];
#pragma unroll
  for (int m = 0; m < 4; ++m)
#pragma unroll
    for (int n = 0; n < 4; ++n) acc[m][n] = (f32x4){0.f, 0.f, 0.f, 0.f};

#define STAGE_A(kt, h, r, slot)                                              \
  gload_lds16(Ab + (size_t)((h) * 128 + (r) * 64) * 1024 + (kt) * 64,        \
              &lA[(slot) * 16384 + ((h) * 128 + (r) * 64 + w * 8) * 64])
#define STAGE_B(kt, h, slot)                                                 \
  gload_lds16(Bb + (size_t)((h) * 64) * 1024 + (kt) * 64,                    \
              &lB[(slot) * 8192 + ((h) * 64 + w * 8) * 64])
#define RD_A(mm, ks) \
  (*reinterpret_cast<const bf16x8*>(&lA[aBase + ((mm) * 16 + fr) * 64 + ((((ks) * 4) + fg) ^ sw) * 8]))
#define RD_B(nn, ks) \
  (*reinterpret_cast<const bf16x8*>(&lB[bBase + ((nn) * 16 + fr) * 64 + ((((ks) * 4) + fg) ^ sw) * 8]))

  // prologue: tile 0 (6 loads) -- in flight while we reduce cval below
  STAGE_A(0, 0, 0, 0); STAGE_A(0, 0, 1, 0); STAGE_A(0, 1, 0, 0); STAGE_A(0, 1, 1, 0);
  STAGE_B(0, 0, 0); STAGE_B(0, 1, 0);

  // ---- fused finalize: cval = sum_col (sum_by pnum) / (sum_by pden) ----
  float vsum = 0.f;
#pragma unroll
  for (int j = 0; j < 2; ++j) {
    const int c = tid + j * 512;
    float d = 0.f, nm = 0.f;
#pragma unroll 8
    for (int b2 = 0; b2 < 32; ++b2) {
      d += pden[b2 * 1024 + c];
      nm += pnum[b2 * 1024 + c];
    }
    vsum += nm / d;
  }
  red[tid] = vsum;
  __syncthreads();
  for (int s = 256; s > 0; s >>= 1) {
    if (tid < s) red[tid] += red[tid + s];
    __syncthreads();
  }
  const float cv = red[0];
  // note: the reduce's __syncthreads drained vmcnt -> tile-0 stages landed.

#pragma unroll 1
  for (int T = 0; T < NKT; ++T) {
    const int slot = T & 1, ns = slot ^ 1;
    const bool pf = (T + 1) < NKT;
    if (pf) { STAGE_A(T + 1, 0, 0, ns); STAGE_A(T + 1, 0, 1, ns); }
    if (pf) asm volatile("s_waitcnt vmcnt(2)" ::: "memory");
    else    asm volatile("s_waitcnt vmcnt(0)" ::: "memory");
    __builtin_amdgcn_s_barrier();
    __builtin_amdgcn_sched_barrier(0);

    const int aBase = slot * 16384 + wr * 4096;
    const int bBase = slot * 8192 + wc * 4096;
    bf16x8 af[2], bfv[4];
    // phase 1: ks=0, m 0..1
#pragma unroll
    for (int n = 0; n < 4; ++n) bfv[n] = RD_B(n, 0);
    af[0] = RD_A(0, 0); af[1] = RD_A(1, 0);
    if (pf) { STAGE_A(T + 1, 1, 0, ns); STAGE_A(T + 1, 1, 1, ns); }
    __builtin_amdgcn_s_setprio(1);
#pragma unroll
    for (int m = 0; m < 2; ++m)
#pragma unroll
      for (int n = 0; n < 4; ++n)
        acc[m][n] = __builtin_amdgcn_mfma_f32_16x16x32_bf16(af[m], bfv[n], acc[m][n], 0, 0, 0);
    __builtin_amdgcn_s_setprio(0);
    __builtin_amdgcn_s_barrier();
    __builtin_amdgcn_sched_barrier(0);
    // phase 2: ks=0, m 2..3
    af[0] = RD_A(2, 0); af[1] = RD_A(3, 0);
    if (pf) STAGE_B(T + 1, 0, ns);
    __builtin_amdgcn_s_setprio(1);
#pragma unroll
    for (int m = 0; m < 2; ++m)
#pragma unroll
      for (int n = 0; n < 4; ++n)
        acc[m + 2][n] = __builtin_amdgcn_mfma_f32_16x16x32_bf16(af[m], bfv[n], acc[m + 2][n], 0, 0, 0);
    __builtin_amdgcn_s_setprio(0);
    __builtin_amdgcn_s_barrier();
    __builtin_amdgcn_sched_barrier(0);
    // phase 3: ks=1, m 0..1
#pragma unroll
    for (int n = 0; n < 4; ++n) bfv[n] = RD_B(n, 1);
    af[0] = RD_A(0, 1); af[1] = RD_A(1, 1);
    if (pf) STAGE_B(T + 1, 1, ns);
    __builtin_amdgcn_s_setprio(1);
#pragma unroll
    for (int m = 0; m < 2; ++m)
#pragma unroll
      for (int n = 0; n < 4; ++n)
        acc[m][n] = __builtin_amdgcn_mfma_f32_16x16x32_bf16(af[m], bfv[n], acc[m][n], 0, 0, 0);
    __builtin_amdgcn_s_setprio(0);
    __builtin_amdgcn_s_barrier();
    __builtin_amdgcn_sched_barrier(0);
    // phase 4: ks=1, m 2..3
    af[0] = RD_A(2, 1); af[1] = RD_A(3, 1);
    __builtin_amdgcn_s_setprio(1);
#pragma unroll
    for (int m = 0; m < 2; ++m)
#pragma unroll
      for (int n = 0; n < 4; ++n)
        acc[m + 2][n] = __builtin_amdgcn_mfma_f32_16x16x32_bf16(af[m], bfv[n], acc[m + 2][n], 0, 0, 0);
    __builtin_amdgcn_s_setprio(0);
    __builtin_amdgcn_s_barrier();
    __builtin_amdgcn_sched_barrier(0);
  }
#undef STAGE_A
#undef STAGE_B
#undef RD_A
#undef RD_B

#pragma unroll
  for (int n = 0; n < 4; ++n) {
    const int col = n0 + wc * 64 + n * 16 + fr;
    const float bs = bias[col];
#pragma unroll
    for (int m = 0; m < 4; ++m) {
      const int row = m0 + wr * 64 + m * 16 + fg * 4;
#pragma unroll
      for (int r = 0; r < 4; ++r) {
        float v = acc[m][n][r] + bs;
        v = cv / (1.f + __expf(-v));
        C[(size_t)(row + r) * 1024 + col] = v;
      }
    }
  }
}

extern "C" void kernel_launch(void* const* d_in, const int* in_sizes, int n_in,
                              void* d_out, int out_size, void* d_ws, size_t ws_size,
                              hipStream_t stream) {
  const float* q = (const float*)d_in[0];
  const float* Wq = (const float*)d_in[1];
  const float* bq = (const float*)d_in[2];
  const float* Wk = (const float*)d_in[3];
  const float* bk = (const float*)d_in[4];
  const float* Wv = (const float*)d_in[5];
  const float* bv = (const float*)d_in[6];
  float* out = (float*)d_out;

  char* ws = (char*)d_ws;
  bf16_t* qb = (bf16_t*)ws;                                  // 16 MB
  bf16_t* Wkv = (bf16_t*)(ws + (size_t)16 * 1024 * 1024);    // 4 MB interleaved
  bf16_t* Wqb = (bf16_t*)(ws + (size_t)20 * 1024 * 1024);    // 2 MB
  float* bkv = (float*)(ws + (size_t)22 * 1024 * 1024);      // 8 KB
  float* pden = (float*)(ws + (size_t)23 * 1024 * 1024);     // 128 KB
  float* pnum = (float*)(ws + (size_t)23 * 1024 * 1024 + 131072);

  cvt_all<<<5633, 256, 0, stream>>>(q, Wk, Wv, Wq, bk, bv, qb, Wkv, Wqb, bkv);
  gemm_kv8<<<256, 512, 0, stream>>>(qb, Wkv, bkv, pden, pnum);
  gemm_q8<<<256, 512, 0, stream>>>(qb, Wqb, bq, pden, pnum, out);
}